// Round 16
// baseline (559.253 us; speedup 1.0000x reference)
//
#include <hip/hip_runtime.h>

#define N_NODESC 50000
#define N_EDGESC 600000
#define HID 128
#define LAYERS 3
#define N_GRAPHSC 16
#define OUT_DIM 14
#define GEN_EPS 1e-7f
#define BN_EPS 1e-5f
#define CSR_BLK 196      // ceil(50000/256) — co-resident (<=256 CUs)
#define EMB_BLK 6250     // embed blocks (8 rows each)
#define WF_BLK 192       // wfrag tail blocks
#define CNT_BLK 2344     // degree-count tail blocks
#define SCT_BLK 2344     // scatter blocks
#define BNR_BLK 64       // bn-reduce tail blocks (layer 0)
#define GEMM_BLK 782     // ceil(50000/64)
#define LOG2E 1.44269504f

typedef short bf16x8 __attribute__((ext_vector_type(8)));
typedef float f32x4 __attribute__((ext_vector_type(4)));

__device__ __forceinline__ unsigned short f2bf(float f) {
    union { float f; unsigned u; } v; v.f = f;
    unsigned r = v.u + 0x7FFF + ((v.u >> 16) & 1);  // RNE
    return (unsigned short)(r >> 16);
}
__device__ __forceinline__ float bf_lo(unsigned u) {
    return __uint_as_float(u << 16);
}
__device__ __forceinline__ float bf_hi(unsigned u) {
    return __uint_as_float(u & 0xFFFF0000u);
}
__device__ __forceinline__ float bfs(unsigned short u) {
    return __uint_as_float(((unsigned)u) << 16);
}

// ---------------- embed (+layer-0 BN partials) + wfrag tail + count tail ----
__global__ void k_embed(const int* __restrict__ f0, const int* __restrict__ f1,
                        const float4* __restrict__ W0, const float4* __restrict__ W1,
                        uint2* __restrict__ hvb2, float* __restrict__ part,
                        const float* __restrict__ W, unsigned short* __restrict__ wf,
                        const int* __restrict__ edst, int* __restrict__ deg) {
    int tid = threadIdx.x;
    if (blockIdx.x >= EMB_BLK + WF_BLK) {
        int e = (blockIdx.x - EMB_BLK - WF_BLK) * 256 + tid;
        if (e < N_EDGESC) atomicAdd(&deg[edst[e]], 1);
        return;
    }
    if (blockIdx.x >= EMB_BLK) {
        int i = (blockIdx.x - EMB_BLK) * 256 + tid;
        if (i < LAYERS * 16384) {
            int j = i & 7;
            int lane = (i >> 3) & 63;
            int nt = (i >> 9) & 7;
            int ks = (i >> 12) & 3;
            int l = i >> 14;
            int k = ks * 32 + (lane >> 4) * 8 + j;
            int n = nt * 16 + (lane & 15);
            wf[i] = f2bf(W[(size_t)l * HID * HID + k * HID + n]);
        }
        return;
    }
    __shared__ float sh[1024], sh2[1024];
    int i = blockIdx.x * 256 + tid;
    int v = i >> 5, c4 = i & 31;
    float4 a = W0[f0[v] * 32 + c4];
    float4 b = W1[f1[v] * 32 + c4];
    float4 o = make_float4(a.x + b.x, a.y + b.y, a.z + b.z, a.w + b.w);
    uint2 ob;
    ob.x = (unsigned)f2bf(o.x) | ((unsigned)f2bf(o.y) << 16);
    ob.y = (unsigned)f2bf(o.z) | ((unsigned)f2bf(o.w) << 16);
    hvb2[i] = ob;
    sh[tid * 4 + 0] = o.x; sh2[tid * 4 + 0] = o.x * o.x;
    sh[tid * 4 + 1] = o.y; sh2[tid * 4 + 1] = o.y * o.y;
    sh[tid * 4 + 2] = o.z; sh2[tid * 4 + 2] = o.z * o.z;
    sh[tid * 4 + 3] = o.w; sh2[tid * 4 + 3] = o.w * o.w;
    __syncthreads();
    if (tid < 128) {
        int c4i = tid >> 2, j = tid & 3;
        float s = 0.f, s2 = 0.f;
#pragma unroll
        for (int r = 0; r < 8; r++) {
            s += sh[(r * 32 + c4i) * 4 + j];
            s2 += sh2[(r * 32 + c4i) * 4 + j];
        }
        part[(size_t)blockIdx.x * 256 + tid] = s;
        part[(size_t)blockIdx.x * 256 + 128 + tid] = s2;
    }
}

// ---------------- single-pass CSR scan (decoupled lookback) -----------------
// status[b]: (state<<32)|value; state 1 = aggregate, 2 = inclusive prefix.
// 196 blocks <= CU count -> all co-resident; zeroed by host memset each call.
__global__ void k_csr(const int* __restrict__ deg,
                      unsigned long long* __restrict__ status,
                      int* __restrict__ row_ptr, int* __restrict__ cursor) {
    __shared__ int sh[256];
    __shared__ int s_prev;
    int t = threadIdx.x, b = blockIdx.x;
    int i = b * 256 + t;
    int d = (i < N_NODESC) ? deg[i] : 0;
    sh[t] = d;
    __syncthreads();
    for (int off = 1; off < 256; off <<= 1) {
        int add = (t >= off) ? sh[t - off] : 0;
        __syncthreads();
        sh[t] += add;
        __syncthreads();
    }
    int agg = sh[255];
    if (t == 0) {
        unsigned long long st0 =
            ((unsigned long long)((b == 0) ? 2 : 1) << 32) | (unsigned)agg;
        atomicExch(&status[b], st0);
        if (b == 0) s_prev = 0;
    }
    if (b > 0 && t < 64) {
        int run = 0;
        int q = b - 1 - t;
        for (;;) {
            unsigned long long st;
            if (q >= 0) {
                do { st = atomicAdd(&status[q], 0ull); } while ((st >> 32) == 0);
            } else {
                st = (2ull << 32);   // virtual predecessor: prefix 0
            }
            int isDone = ((st >> 32) == 2ull);
            unsigned long long mask2 = __ballot(isDone);
            int first2 = (int)__ffsll((long long)mask2) - 1;  // -1 if none
            int lim = (first2 >= 0) ? first2 : 63;
            int contrib = (t <= lim) ? (int)(unsigned)(st & 0xFFFFFFFFull) : 0;
#pragma unroll
            for (int o = 1; o < 64; o <<= 1)
                contrib += __shfl_xor(contrib, o, 64);
            run += contrib;
            if (first2 >= 0) break;
            q -= 64;
        }
        if (t == 0) {
            atomicExch(&status[b], (2ull << 32) | (unsigned)(run + agg));
            s_prev = run;
        }
    }
    __syncthreads();
    if (i < N_NODESC) {
        int rp = s_prev + sh[t] - d;   // exclusive
        row_ptr[i] = rp;
        cursor[i] = rp;
    }
    if (i == 0) row_ptr[N_NODESC] = N_EDGESC;
}

// ---------------- scatter + layer-0 BN reduce (fused grid) ------------------
// pack = (src<<8) | f01*8
__global__ void k_scatter(const int* __restrict__ dst, const int* __restrict__ src,
                          const int* __restrict__ f0, const int* __restrict__ f1,
                          int* __restrict__ cursor, int* __restrict__ csr_pack,
                          const float* __restrict__ part, float* __restrict__ gsum) {
    int tid = threadIdx.x;
    if (blockIdx.x >= SCT_BLK) {
        int bb = blockIdx.x - SCT_BLK;
        int rows = (EMB_BLK + BNR_BLK - 1) / BNR_BLK;
        int r0 = bb * rows;
        int r1 = min(r0 + rows, EMB_BLK);
        float s = 0.f;
        for (int p = r0; p < r1; p++) s += part[(size_t)p * 256 + tid];
        atomicAdd(&gsum[tid], s);
        return;
    }
    int i = blockIdx.x * 256 + tid;
    if (i < N_EDGESC) {
        int pos = atomicAdd(&cursor[dst[i]], 1);
        csr_pack[pos] = (src[i] << 8) | ((f0[i] * 3 + f1[i]) * 8);
    }
}

// ---------------- FUSED: BN-inline agg -> LDS -> MFMA GEMM ------------------
// Block = 64 nodes, 512 threads. Gathers from hin (pre-BN bf16), applies
// BN+ReLU inline; MFMA; epilogue: bias + skip (hin->hout) + stats or pooling.
// Last layer: last-finishing block computes the final output linear.
__global__ __launch_bounds__(512) void k_aggemm(
    const unsigned* __restrict__ hin, unsigned short* __restrict__ hout,
    const int* __restrict__ row_ptr, const int* __restrict__ csr_pack,
    const float* __restrict__ e0, const float* __restrict__ e1,
    const float* __restrict__ beta_p, const unsigned short* __restrict__ wf,
    const float* __restrict__ b, const float* __restrict__ gsum,
    const float* __restrict__ gamma, const float* __restrict__ betab,
    float* __restrict__ gsum_next, float* __restrict__ hg,
    const float* __restrict__ Wo, const float* __restrict__ bo,
    float* __restrict__ out, int* __restrict__ fctr) {
    __shared__ float2 sh_et[18 * 64];      // 9216 B
    __shared__ unsigned x_tile[64 * 64];   // 16384 B: [row][rot col]
    __shared__ float shs[512], shs2[512];  // 4096 B
    __shared__ int s_last;
    int tid = threadIdx.x;
    for (int i = tid; i < 18 * 64; i += 512) {
        int f = i >> 6, ln = i & 63;
        int a = f / 3, bb = f - 3 * a;
        float2 ea = *(const float2*)(e0 + a * HID + 2 * ln);
        float2 eb = *(const float2*)(e1 + bb * HID + 2 * ln);
        sh_et[i] = make_float2(ea.x + eb.x, ea.y + eb.y);
    }
    int w = tid >> 6, lane = tid & 63;
    int m0 = blockIdx.x * 64;
    const float bl2 = (*beta_p) * LOG2E;
    const float invN = 1.f / (float)N_NODESC;
    int cch = lane * 2;
    float mu0 = gsum[cch] * invN, mu1 = gsum[cch + 1] * invN;
    float var0 = gsum[128 + cch] * invN - mu0 * mu0;
    float var1 = gsum[129 + cch] * invN - mu1 * mu1;
    float sc0 = gamma[cch] * rsqrtf(var0 + BN_EPS);
    float sc1 = gamma[cch + 1] * rsqrtf(var1 + BN_EPS);
    float sf0 = betab[cch] - mu0 * sc0;
    float sf1 = betab[cch + 1] - mu1 * sc1;
    __syncthreads();

    const char* hinc = (const char*)hin;
    const char* etc = (const char*)sh_et;
    unsigned lane4 = (unsigned)lane * 4;
    unsigned lane8 = (unsigned)lane * 8;

#define AGG_BODY(J)                                                         \
    {                                                                       \
        int pack = __shfl(pk, (J), 64);                                     \
        unsigned u = *(const unsigned*)(hinc +                              \
                        ((((unsigned)pack) & 0xFFFFFF00u) + lane4));        \
        float2 t = *(const float2*)(etc +                                   \
                        (((((unsigned)pack) & 0xFFu) << 6) + lane8));       \
        float a0 = fmaxf(fmaf(bf_lo(u), sc0, sf0), 0.f);                    \
        float a1 = fmaxf(fmaf(bf_hi(u), sc1, sf1), 0.f);                    \
        float r0 = fmaxf(a0 + t.x, 0.f);                                    \
        float r1 = fmaxf(a1 + t.y, 0.f);                                    \
        float w0 = exp2f(r0 * bl2);                                         \
        float w1 = exp2f(r1 * bl2);                                         \
        d0 += w0; d1 += w1;                                                 \
        n0 = fmaf(r0, w0, n0); n1 = fmaf(r1, w1, n1);                       \
    }

    // ---- phase 1: aggregation, 8 nodes per wave ----
    for (int i = 0; i < 8; i++) {
        int row = w * 8 + i;
        int v = m0 + row;
        int vc = min(v, N_NODESC - 1);
        unsigned su = hin[(size_t)vc * 64 + lane];
        float h10 = fmaxf(fmaf(bf_lo(su), sc0, sf0), 0.f);
        float h11 = fmaxf(fmaf(bf_hi(su), sc1, sf1), 0.f);
        int p0 = row_ptr[vc];
        int deg = (v < N_NODESC) ? (row_ptr[vc + 1] - p0) : 0;
        float n0 = 0.f, n1 = 0.f, d0 = 0.f, d1 = 0.f;
        for (int base = 0; base < deg; base += 64) {
            int idx = base + lane;
            int pk = (idx < deg) ? csr_pack[p0 + idx] : 0;
            int jn = min(64, deg - base);
            int j = 0;
            for (; j + 2 <= jn; j += 2) {
                AGG_BODY(j)
                AGG_BODY(j + 1)
            }
            if (j < jn) AGG_BODY(j)
        }
        float ox = h10 + (deg ? __fdividef(n0, d0) + GEN_EPS : 0.f);
        float oy = h11 + (deg ? __fdividef(n1, d1) + GEN_EPS : 0.f);
        x_tile[row * 64 + ((lane + row * 4) & 63)] =
            (unsigned)f2bf(ox) | ((unsigned)f2bf(oy) << 16);
    }
#undef AGG_BODY
    __syncthreads();

    // ---- phase 2: MFMA ----
    int rw = w & 3, chh = w >> 2;
    int mrow = lane & 15, grp = lane >> 4;
    int rbase = rw * 16 + mrow;
    bf16x8 af[4];
#pragma unroll
    for (int ks = 0; ks < 4; ks++) {
        int col = ks * 16 + grp * 4;
        int colr = (col + rbase * 4) & 63;
        af[ks] = *(const bf16x8*)&x_tile[rbase * 64 + colr];
    }
    f32x4 acc[4];
#pragma unroll
    for (int nt = 0; nt < 4; nt++) acc[nt] = (f32x4){0.f, 0.f, 0.f, 0.f};
#pragma unroll
    for (int nt = 0; nt < 4; nt++) {
        int ntg = chh * 4 + nt;
#pragma unroll
        for (int ks = 0; ks < 4; ks++) {
            bf16x8 bfr = *(const bf16x8*)(wf +
                (size_t)((ks * 8 + ntg) * 64 + lane) * 8);
            acc[nt] = __builtin_amdgcn_mfma_f32_16x16x32_bf16(
                af[ks], bfr, acc[nt], 0, 0, 0);
        }
    }
    // epilogue: bias + skip (hin -> hout) + stats or pooling
    const unsigned short* hin_s = (const unsigned short*)hin;
    int gA = m0 / 3125;
    int boundary = (gA + 1) * 3125;
#pragma unroll
    for (int nt = 0; nt < 4; nt++) {
        int col = chh * 64 + nt * 16 + mrow;
        float bias = b[col];
        float s = 0.f, s2 = 0.f;
#pragma unroll
        for (int r = 0; r < 4; r++) {
            int v = m0 + rw * 16 + grp * 4 + r;
            if (v < N_NODESC) {
                size_t idx = (size_t)v * HID + col;
                float o = acc[nt][r] + bias + bfs(hin_s[idx]);
                hout[idx] = f2bf(o);
                if (hg) {
                    if (v < boundary) s += o; else s2 += o;
                } else {
                    s += o; s2 += o * o;
                }
            }
        }
        s  += __shfl_xor(s, 16, 64);  s  += __shfl_xor(s, 32, 64);
        s2 += __shfl_xor(s2, 16, 64); s2 += __shfl_xor(s2, 32, 64);
        if (lane < 16) { shs[rw * 128 + col] = s; shs2[rw * 128 + col] = s2; }
    }
    __syncthreads();
    if (hg) {
        int gB = min(m0 + 63, N_NODESC - 1) / 3125;
        if (tid < 128) {
            atomicAdd(&hg[gA * 128 + tid],
                shs[tid] + shs[128 + tid] + shs[256 + tid] + shs[384 + tid]);
        } else if (tid < 256 && gB != gA) {
            int c = tid - 128;
            atomicAdd(&hg[gB * 128 + c],
                shs2[c] + shs2[128 + c] + shs2[256 + c] + shs2[384 + c]);
        }
        // last-finishing block computes the output linear
        __threadfence();
        if (tid == 0) s_last = atomicAdd(fctr, 1);
        __syncthreads();
        if (s_last == (int)gridDim.x - 1) {
            __threadfence();
            if (tid < N_GRAPHSC * OUT_DIM) {
                int g = tid / OUT_DIM, o = tid % OUT_DIM;
                const float inv = (float)N_GRAPHSC / (float)N_NODESC;
                float acc2 = bo[o];
                for (int k = 0; k < HID; k++)
                    acc2 += hg[g * HID + k] * inv * Wo[k * OUT_DIM + o];
                out[tid] = acc2;
            }
        }
    } else if (gsum_next) {
        if (tid < 128) {
            atomicAdd(&gsum_next[tid],
                shs[tid] + shs[128 + tid] + shs[256 + tid] + shs[384 + tid]);
        } else if (tid < 256) {
            int c = tid - 128;
            atomicAdd(&gsum_next[tid],
                shs2[c] + shs2[128 + c] + shs2[256 + c] + shs2[384 + c]);
        }
    }
}

extern "C" void kernel_launch(void* const* d_in, const int* in_sizes, int n_in,
                              void* d_out, int out_size, void* d_ws, size_t ws_size,
                              hipStream_t stream) {
    const int* node_feat0 = (const int*)d_in[0];
    const int* node_feat1 = (const int*)d_in[1];
    const int* edge_feat0 = (const int*)d_in[2];
    const int* edge_feat1 = (const int*)d_in[3];
    const int* edge_src   = (const int*)d_in[4];
    const int* edge_dst   = (const int*)d_in[5];
    const float* W_node0   = (const float*)d_in[8];
    const float* W_node1   = (const float*)d_in[9];
    const float* edge_emb0 = (const float*)d_in[10];
    const float* edge_emb1 = (const float*)d_in[11];
    const float* beta      = (const float*)d_in[12];
    const float* mlp_W     = (const float*)d_in[13];
    const float* mlp_b     = (const float*)d_in[14];
    const float* bn_gamma  = (const float*)d_in[15];
    const float* bn_beta   = (const float*)d_in[16];
    const float* W_out     = (const float*)d_in[17];
    const float* b_out     = (const float*)d_in[18];
    float* out = (float*)d_out;

    char* ws = (char*)d_ws;
    size_t off = 0;
    auto alloc = [&](size_t bytes) -> void* {
        void* p = ws + off;
        off += (bytes + 255) & ~(size_t)255;
        return p;
    };
    unsigned short* hvA = (unsigned short*)alloc((size_t)N_NODESC * HID * 2);
    unsigned short* hvB = (unsigned short*)alloc((size_t)N_NODESC * HID * 2);
    float* bnpart  = (float*)alloc((size_t)EMB_BLK * 256 * 4);
    unsigned short* wfrag = (unsigned short*)alloc((size_t)LAYERS * 16384 * 2);
    int* row_ptr   = (int*)alloc((N_NODESC + 1) * 4);
    int* cursor    = (int*)alloc(N_NODESC * 4);
    int* csr_pack  = (int*)alloc((size_t)N_EDGESC * 4);
    // ---- contiguous zero-span: deg | status | gsums | hg | fctr ----
    int* deg = (int*)alloc(N_NODESC * 4);
    unsigned long long* status = (unsigned long long*)alloc(CSR_BLK * 8);
    float* gsums = (float*)alloc(LAYERS * 256 * 4);
    float* hg    = (float*)alloc(N_GRAPHSC * HID * 4);
    int* fctr    = (int*)alloc(256);
    size_t zero_bytes = (size_t)(((char*)fctr + 256) - (char*)deg);

    hipMemsetAsync(deg, 0, zero_bytes, stream);

    // ---- embed (+layer-0 BN partials) + wfrag + degree count, one grid ----
    k_embed<<<EMB_BLK + WF_BLK + CNT_BLK, 256, 0, stream>>>(
        node_feat0, node_feat1, (const float4*)W_node0, (const float4*)W_node1,
        (uint2*)hvA, bnpart, mlp_W, wfrag, edge_dst, deg);

    // ---- single-pass CSR scan ----
    k_csr<<<CSR_BLK, 256, 0, stream>>>(deg, status, row_ptr, cursor);

    // ---- scatter + layer-0 BN reduce ----
    k_scatter<<<SCT_BLK + BNR_BLK, 256, 0, stream>>>(
        edge_dst, edge_src, edge_feat0, edge_feat1, cursor, csr_pack,
        bnpart, gsums);

    // ---- layers (ping-pong hvA/hvB; last layer pools + emits output) ----
    unsigned short* hin = hvA;
    unsigned short* hout = hvB;
    for (int l = 0; l < LAYERS; l++) {
        float* gsum = gsums + l * 256;
        float* gnext = (l + 1 < LAYERS) ? gsums + (l + 1) * 256 : nullptr;
        float* hgp = (l == LAYERS - 1) ? hg : nullptr;
        k_aggemm<<<GEMM_BLK, 512, 0, stream>>>(
            (const unsigned*)hin, hout, row_ptr, csr_pack,
            edge_emb0 + (size_t)l * 6 * HID, edge_emb1 + (size_t)l * 3 * HID,
            beta + l, wfrag + (size_t)l * 16384, mlp_b + l * HID,
            gsum, bn_gamma + l * HID, bn_beta + l * HID, gnext, hgp,
            W_out, b_out, out, fctr);
        unsigned short* tmp = hin; hin = hout; hout = tmp;
    }
}